// Round 1
// baseline (203.597 us; speedup 1.0000x reference)
//
#include <hip/hip_runtime.h>
#include <math.h>

#define NREL   3
#define EDGES  200000
#define DIM    128
#define EDGES_PER_BLOCK 8

__global__ __launch_bounds__(256) void distmult_kernel(
    const float* __restrict__ h_drug,
    const float* __restrict__ h_disease,
    const float* __restrict__ W,
    const int*   __restrict__ drug_src,
    const int*   __restrict__ dis_dst,
    const int*   __restrict__ dis_src,
    const int*   __restrict__ drug_dst,
    float*       __restrict__ out)
{
    const int ro    = blockIdx.y;            // 0..5  (0..2 fwd, 3..5 rev)
    const int group = threadIdx.x >> 5;      // 0..7  (edge within block)
    const int lane  = threadIdx.x & 31;      // 0..31 (covers D=128 as float4)
    const int e     = blockIdx.x * EDGES_PER_BLOCK + group;
    if (e >= EDGES) return;

    const float* a_row;
    const float* b_row;
    if (ro < NREL) {
        // s_fwd[r][e] = sum_d h_drug[drug_src]*W[r]*h_disease[dis_dst]
        const int r = ro;
        a_row = h_drug    + (long long)drug_src[r * EDGES + e] * DIM;
        b_row = h_disease + (long long)dis_dst [r * EDGES + e] * DIM;
    } else {
        // s_rev[r][e] = sum_d h_disease[dis_src]*W[NREL+r]*h_drug[drug_dst]
        const int r = ro - NREL;
        a_row = h_disease + (long long)dis_src [r * EDGES + e] * DIM;
        b_row = h_drug    + (long long)drug_dst[r * EDGES + e] * DIM;
    }

    const float4 a4 = ((const float4*)a_row)[lane];
    const float4 b4 = ((const float4*)b_row)[lane];
    const float4 w4 = ((const float4*)(W + ro * DIM))[lane];

    float p = a4.x * w4.x * b4.x
            + a4.y * w4.y * b4.y
            + a4.z * w4.z * b4.z
            + a4.w * w4.w * b4.w;

    // Butterfly reduction across the 32 lanes of this edge-group.
    // Masks < 32 keep data within each 32-lane half of the 64-lane wave.
    #pragma unroll
    for (int m = 16; m >= 1; m >>= 1)
        p += __shfl_xor(p, m, 64);

    if (lane == 0) {
        out[(long long)ro * EDGES + e] = 1.0f / (1.0f + __expf(-p));
    }
}

extern "C" void kernel_launch(void* const* d_in, const int* in_sizes, int n_in,
                              void* d_out, int out_size, void* d_ws, size_t ws_size,
                              hipStream_t stream) {
    const float* h_drug    = (const float*)d_in[0];
    const float* h_disease = (const float*)d_in[1];
    const float* W         = (const float*)d_in[2];
    const int*   drug_src  = (const int*)d_in[3];
    const int*   dis_dst   = (const int*)d_in[4];
    const int*   dis_src   = (const int*)d_in[5];
    const int*   drug_dst  = (const int*)d_in[6];
    float*       out       = (float*)d_out;

    dim3 grid(EDGES / EDGES_PER_BLOCK, 2 * NREL);  // (25000, 6)
    distmult_kernel<<<grid, 256, 0, stream>>>(
        h_drug, h_disease, W, drug_src, dis_dst, dis_src, drug_dst, out);
}

// Round 2
// 196.035 us; speedup vs baseline: 1.0386x; 1.0386x over previous
//
#include <hip/hip_runtime.h>
#include <math.h>

#define NREL    3
#define EDGES   200000
#define HALF_E  100000
#define DIM     128
#define CHUNKF  32            // floats per D-chunk
#define NCHUNK  4
#define BATCHES 3125          // HALF_E / 32 edges handled per block
#define J_PER   (6 * BATCHES) // 18750 (ro, batch) pairs per XCD slot

// Pass 1: per-chunk partial triple-dot, accumulated into out via atomicAdd.
// chunk is pinned to an XCD pair via blockIdx % 8 so each XCD's L2 only
// holds that chunk's 3.25 MB sub-table (h_drug 1.0 MB + h_disease 2.25 MB).
__global__ __launch_bounds__(256) void distmult_partial(
    const float* __restrict__ h_drug,
    const float* __restrict__ h_disease,
    const float* __restrict__ W,
    const int*   __restrict__ drug_src,
    const int*   __restrict__ dis_dst,
    const int*   __restrict__ dis_src,
    const int*   __restrict__ drug_dst,
    float*       __restrict__ out)
{
    const int b     = blockIdx.x;
    const int slot  = b & 7;        // XCD slot (round-robin dispatch)
    const int chunk = slot >> 1;    // 0..3  -> D range [32*chunk, 32*chunk+32)
    const int half  = slot & 1;     // 2 XCDs share a chunk, split edge range
    const int j     = b >> 3;       // 0..18749
    const int ro    = j / BATCHES;  // 0..5  (0..2 fwd, 3..5 rev)
    const int batch = j % BATCHES;

    const int eg   = threadIdx.x >> 3;  // 0..31 edge within block
    const int lane = threadIdx.x & 7;   // 0..7  float4 lane within chunk
    const int e    = half * HALF_E + batch * 32 + eg;

    const float* a_row;
    const float* b_row;
    if (ro < NREL) {
        const int r = ro;
        const int ia = __builtin_nontemporal_load(&drug_src[r * EDGES + e]);
        const int ib = __builtin_nontemporal_load(&dis_dst [r * EDGES + e]);
        a_row = h_drug    + (size_t)ia * DIM;
        b_row = h_disease + (size_t)ib * DIM;
    } else {
        const int r = ro - NREL;
        const int ia = __builtin_nontemporal_load(&dis_src [r * EDGES + e]);
        const int ib = __builtin_nontemporal_load(&drug_dst[r * EDGES + e]);
        a_row = h_disease + (size_t)ia * DIM;
        b_row = h_drug    + (size_t)ib * DIM;
    }

    const int off = chunk * CHUNKF;
    const float4 a4 = ((const float4*)(a_row + off))[lane];
    const float4 b4 = ((const float4*)(b_row + off))[lane];
    const float4 w4 = ((const float4*)(W + ro * DIM + off))[lane];

    float p = a4.x * w4.x * b4.x
            + a4.y * w4.y * b4.y
            + a4.z * w4.z * b4.z
            + a4.w * w4.w * b4.w;

    // Reduce across the 8 lanes of this edge-group (stays within the group).
    p += __shfl_xor(p, 4, 64);
    p += __shfl_xor(p, 2, 64);
    p += __shfl_xor(p, 1, 64);

    if (lane == 0) {
        atomicAdd(&out[(size_t)ro * EDGES + e], p);
    }
}

// Pass 2: in-place sigmoid over the accumulated scores.
__global__ __launch_bounds__(256) void sigmoid_inplace(float* __restrict__ out)
{
    const int i = blockIdx.x * 256 + threadIdx.x;   // float4 index
    if (i >= (2 * NREL * EDGES) / 4) return;
    float4 v = ((float4*)out)[i];
    v.x = 1.0f / (1.0f + __expf(-v.x));
    v.y = 1.0f / (1.0f + __expf(-v.y));
    v.z = 1.0f / (1.0f + __expf(-v.z));
    v.w = 1.0f / (1.0f + __expf(-v.w));
    ((float4*)out)[i] = v;
}

extern "C" void kernel_launch(void* const* d_in, const int* in_sizes, int n_in,
                              void* d_out, int out_size, void* d_ws, size_t ws_size,
                              hipStream_t stream) {
    const float* h_drug    = (const float*)d_in[0];
    const float* h_disease = (const float*)d_in[1];
    const float* W         = (const float*)d_in[2];
    const int*   drug_src  = (const int*)d_in[3];
    const int*   dis_dst   = (const int*)d_in[4];
    const int*   dis_src   = (const int*)d_in[5];
    const int*   drug_dst  = (const int*)d_in[6];
    float*       out       = (float*)d_out;

    // out is poisoned 0xAA before every launch — zero it for the atomics.
    hipMemsetAsync(out, 0, (size_t)2 * NREL * EDGES * sizeof(float), stream);

    distmult_partial<<<8 * J_PER, 256, 0, stream>>>(
        h_drug, h_disease, W, drug_src, dis_dst, dis_src, drug_dst, out);

    const int n4 = (2 * NREL * EDGES) / 4;           // 300000
    sigmoid_inplace<<<(n4 + 255) / 256, 256, 0, stream>>>(out);
}

// Round 3
// 166.284 us; speedup vs baseline: 1.2244x; 1.1789x over previous
//
#include <hip/hip_runtime.h>
#include <math.h>

#define NREL    3
#define EDGES   200000
#define DIM     128
#define CHUNKF  32            // floats per D-chunk
#define PASSES  5             // edge-chunks per thread (software pipeline)
#define BATCH   625           // EDGES / (PASSES*64)
#define JPER    (6 * BATCH)   // (ro,batch) pairs per XCD slot

// Pass 1: per-chunk partial triple-dot. chunk pinned to an XCD pair via
// blockIdx%8 (verified R2: FETCH 418->32 MB). Partials: chunk0 -> out,
// chunks 1..3 -> ws, all via nontemporal stores to avoid evicting the
// pinned 3.25 MB sub-table from the XCD's 4 MiB L2.
__global__ __launch_bounds__(256) void distmult_partial(
    const float* __restrict__ h_drug,
    const float* __restrict__ h_disease,
    const float* __restrict__ W,
    const int*   __restrict__ drug_src,
    const int*   __restrict__ dis_dst,
    const int*   __restrict__ dis_src,
    const int*   __restrict__ drug_dst,
    float*       __restrict__ part0,   // = d_out, chunk 0 partials
    float*       __restrict__ partw)   // = d_ws,  chunks 1..3 partials
{
    const int b     = blockIdx.x;
    const int slot  = b & 7;        // XCD slot
    const int chunk = slot >> 1;    // 0..3 -> D range [32*chunk, +32)
    const int half  = slot & 1;     // 2 XCDs per chunk, interleaved 32-edge groups
    const int j     = b >> 3;
    const int ro    = j / BATCH;    // 0..5 (0..2 fwd, 3..5 rev)
    const int batch = j % BATCH;

    const int eg   = threadIdx.x >> 3;  // 0..31 edge within pass
    const int lane = threadIdx.x & 7;   // 0..7  float4 lane within chunk

    const float* tabA; const float* tabB;
    const int* idxA; const int* idxB;
    if (ro < NREL) {
        tabA = h_drug;    tabB = h_disease;
        idxA = drug_src + (size_t)ro * EDGES;
        idxB = dis_dst  + (size_t)ro * EDGES;
    } else {
        tabA = h_disease; tabB = h_drug;
        idxA = dis_src  + (size_t)(ro - NREL) * EDGES;
        idxB = drug_dst + (size_t)(ro - NREL) * EDGES;
    }

    const int off = chunk * CHUNKF;
    const float4 w4 = ((const float4*)(W + (size_t)ro * DIM + off))[lane];

    float* pbase = (chunk == 0)
        ? part0 + (size_t)ro * EDGES
        : partw + ((size_t)(chunk - 1) * 6 + ro) * EDGES;

    // Issue all index loads up front (10 loads in flight).
    int e[PASSES], ia[PASSES], ib[PASSES];
    #pragma unroll
    for (int p = 0; p < PASSES; ++p) {
        e[p]  = batch * (PASSES * 64) + p * 64 + half * 32 + eg;
        ia[p] = __builtin_nontemporal_load(idxA + e[p]);
        ib[p] = __builtin_nontemporal_load(idxB + e[p]);
    }

    #pragma unroll
    for (int p = 0; p < PASSES; ++p) {
        const float4 a4 = ((const float4*)(tabA + (size_t)ia[p] * DIM + off))[lane];
        const float4 b4 = ((const float4*)(tabB + (size_t)ib[p] * DIM + off))[lane];
        float s = a4.x * w4.x * b4.x
                + a4.y * w4.y * b4.y
                + a4.z * w4.z * b4.z
                + a4.w * w4.w * b4.w;
        s += __shfl_xor(s, 4, 64);
        s += __shfl_xor(s, 2, 64);
        s += __shfl_xor(s, 1, 64);
        if (lane == 0)
            __builtin_nontemporal_store(s, pbase + e[p]);
    }
}

// Pass 2: out = sigmoid(out + ws0 + ws1 + ws2), streaming.
__global__ __launch_bounds__(256) void reduce_sigmoid(
    const float* __restrict__ partw, float* __restrict__ out)
{
    const int i = blockIdx.x * 256 + threadIdx.x;     // float4 index
    if (i >= (6 * EDGES) / 4) return;
    const float4* p0 = (const float4*)out;
    const float4* p1 = (const float4*)(partw);
    const float4* p2 = (const float4*)(partw + (size_t)6 * EDGES);
    const float4* p3 = (const float4*)(partw + (size_t)12 * EDGES);
    float4 v = p0[i], a = p1[i], b = p2[i], c = p3[i];
    v.x += a.x + b.x + c.x;  v.y += a.y + b.y + c.y;
    v.z += a.z + b.z + c.z;  v.w += a.w + b.w + c.w;
    v.x = 1.0f / (1.0f + __expf(-v.x));
    v.y = 1.0f / (1.0f + __expf(-v.y));
    v.z = 1.0f / (1.0f + __expf(-v.z));
    v.w = 1.0f / (1.0f + __expf(-v.w));
    ((float4*)out)[i] = v;
}

// ---- fallback (R2 structure) if ws is too small ----
__global__ __launch_bounds__(256) void distmult_atomic(
    const float* __restrict__ h_drug, const float* __restrict__ h_disease,
    const float* __restrict__ W,
    const int* __restrict__ drug_src, const int* __restrict__ dis_dst,
    const int* __restrict__ dis_src, const int* __restrict__ drug_dst,
    float* __restrict__ out)
{
    const int b = blockIdx.x;
    const int slot = b & 7, chunk = slot >> 1, half = slot & 1;
    const int j = b >> 3;
    const int ro = j / BATCH, batch = j % BATCH;
    const int eg = threadIdx.x >> 3, lane = threadIdx.x & 7;

    const float* tabA; const float* tabB;
    const int* idxA; const int* idxB;
    if (ro < NREL) {
        tabA = h_drug;    tabB = h_disease;
        idxA = drug_src + (size_t)ro * EDGES;
        idxB = dis_dst  + (size_t)ro * EDGES;
    } else {
        tabA = h_disease; tabB = h_drug;
        idxA = dis_src  + (size_t)(ro - NREL) * EDGES;
        idxB = drug_dst + (size_t)(ro - NREL) * EDGES;
    }
    const int off = chunk * CHUNKF;
    const float4 w4 = ((const float4*)(W + (size_t)ro * DIM + off))[lane];

    #pragma unroll
    for (int p = 0; p < PASSES; ++p) {
        const int e = batch * (PASSES * 64) + p * 64 + half * 32 + eg;
        const int ia = __builtin_nontemporal_load(idxA + e);
        const int ib = __builtin_nontemporal_load(idxB + e);
        const float4 a4 = ((const float4*)(tabA + (size_t)ia * DIM + off))[lane];
        const float4 b4 = ((const float4*)(tabB + (size_t)ib * DIM + off))[lane];
        float s = a4.x * w4.x * b4.x + a4.y * w4.y * b4.y
                + a4.z * w4.z * b4.z + a4.w * w4.w * b4.w;
        s += __shfl_xor(s, 4, 64);
        s += __shfl_xor(s, 2, 64);
        s += __shfl_xor(s, 1, 64);
        if (lane == 0) atomicAdd(&out[(size_t)ro * EDGES + e], s);
    }
}

__global__ __launch_bounds__(256) void sigmoid_inplace(float* __restrict__ out)
{
    const int i = blockIdx.x * 256 + threadIdx.x;
    if (i >= (6 * EDGES) / 4) return;
    float4 v = ((float4*)out)[i];
    v.x = 1.0f / (1.0f + __expf(-v.x));
    v.y = 1.0f / (1.0f + __expf(-v.y));
    v.z = 1.0f / (1.0f + __expf(-v.z));
    v.w = 1.0f / (1.0f + __expf(-v.w));
    ((float4*)out)[i] = v;
}

extern "C" void kernel_launch(void* const* d_in, const int* in_sizes, int n_in,
                              void* d_out, int out_size, void* d_ws, size_t ws_size,
                              hipStream_t stream) {
    const float* h_drug    = (const float*)d_in[0];
    const float* h_disease = (const float*)d_in[1];
    const float* W         = (const float*)d_in[2];
    const int*   drug_src  = (const int*)d_in[3];
    const int*   dis_dst   = (const int*)d_in[4];
    const int*   dis_src   = (const int*)d_in[5];
    const int*   drug_dst  = (const int*)d_in[6];
    float*       out       = (float*)d_out;

    const int n4 = (6 * EDGES) / 4;                    // 300000
    const size_t ws_need = (size_t)3 * 6 * EDGES * sizeof(float);  // 14.4 MB

    if (ws_size >= ws_need) {
        distmult_partial<<<8 * JPER, 256, 0, stream>>>(
            h_drug, h_disease, W, drug_src, dis_dst, dis_src, drug_dst,
            out, (float*)d_ws);
        reduce_sigmoid<<<(n4 + 255) / 256, 256, 0, stream>>>((float*)d_ws, out);
    } else {
        hipMemsetAsync(out, 0, (size_t)6 * EDGES * sizeof(float), stream);
        distmult_atomic<<<8 * JPER, 256, 0, stream>>>(
            h_drug, h_disease, W, drug_src, dis_dst, dis_src, drug_dst, out);
        sigmoid_inplace<<<(n4 + 255) / 256, 256, 0, stream>>>(out);
    }
}

// Round 4
// 162.132 us; speedup vs baseline: 1.2557x; 1.0256x over previous
//
#include <hip/hip_runtime.h>
#include <math.h>

#define NREL    3
#define EDGES   200000
#define DIM     128
#define CHUNKF  32            // floats per D-chunk
#define PASSES  5             // edge-chunks per thread (batched pipeline)
#define BATCH   625           // EDGES / (PASSES*64)
#define JPER    (6 * BATCH)   // (ro,batch) pairs per XCD slot

// Pass 1: per-chunk partial triple-dot. chunk pinned to an XCD pair via
// blockIdx%8 (verified R2: FETCH 418->32 MB). Partials: chunk0 -> out,
// chunks 1..3 -> ws, nontemporal stores keep the pinned sub-table in L2.
// R4: loads for ALL passes are issued before any compute -> ~10 row loads
// in flight per wave (was ~2 at VGPR=20), attacking the latency bound.
__global__ __launch_bounds__(256) void distmult_partial(
    const float* __restrict__ h_drug,
    const float* __restrict__ h_disease,
    const float* __restrict__ W,
    const int*   __restrict__ drug_src,
    const int*   __restrict__ dis_dst,
    const int*   __restrict__ dis_src,
    const int*   __restrict__ drug_dst,
    float*       __restrict__ part0,   // = d_out, chunk 0 partials
    float*       __restrict__ partw)   // = d_ws,  chunks 1..3 partials
{
    const int b     = blockIdx.x;
    const int slot  = b & 7;        // XCD slot
    const int chunk = slot >> 1;    // 0..3 -> D range [32*chunk, +32)
    const int half  = slot & 1;     // 2 XCDs per chunk share the edge range
    const int j     = b >> 3;
    const int ro    = j / BATCH;    // 0..5 (0..2 fwd, 3..5 rev)
    const int batch = j % BATCH;

    const int eg   = threadIdx.x >> 3;  // 0..31 edge within pass
    const int lane = threadIdx.x & 7;   // 0..7  float4 lane within chunk

    const float* tabA; const float* tabB;
    const int* idxA; const int* idxB;
    if (ro < NREL) {
        tabA = h_drug;    tabB = h_disease;
        idxA = drug_src + (size_t)ro * EDGES;
        idxB = dis_dst  + (size_t)ro * EDGES;
    } else {
        tabA = h_disease; tabB = h_drug;
        idxA = dis_src  + (size_t)(ro - NREL) * EDGES;
        idxB = drug_dst + (size_t)(ro - NREL) * EDGES;
    }

    const int off = chunk * CHUNKF;
    const float4 w4 = ((const float4*)(W + (size_t)ro * DIM + off))[lane];

    float* pbase = (chunk == 0)
        ? part0 + (size_t)ro * EDGES
        : partw + ((size_t)(chunk - 1) * 6 + ro) * EDGES;

    // Stage 1: all index loads in flight.
    int e[PASSES], ia[PASSES], ib[PASSES];
    #pragma unroll
    for (int p = 0; p < PASSES; ++p) {
        e[p]  = batch * (PASSES * 64) + p * 64 + half * 32 + eg;
        ia[p] = __builtin_nontemporal_load(idxA + e[p]);
        ib[p] = __builtin_nontemporal_load(idxB + e[p]);
    }

    // Stage 2: all row loads in flight (10 x float4 per thread).
    float4 a4[PASSES], b4[PASSES];
    #pragma unroll
    for (int p = 0; p < PASSES; ++p) {
        a4[p] = ((const float4*)(tabA + (size_t)ia[p] * DIM + off))[lane];
        b4[p] = ((const float4*)(tabB + (size_t)ib[p] * DIM + off))[lane];
    }

    // Stage 3: compute, reduce across 8 lanes, store.
    #pragma unroll
    for (int p = 0; p < PASSES; ++p) {
        float s = a4[p].x * w4.x * b4[p].x
                + a4[p].y * w4.y * b4[p].y
                + a4[p].z * w4.z * b4[p].z
                + a4[p].w * w4.w * b4[p].w;
        s += __shfl_xor(s, 4, 64);
        s += __shfl_xor(s, 2, 64);
        s += __shfl_xor(s, 1, 64);
        if (lane == 0)
            __builtin_nontemporal_store(s, pbase + e[p]);
    }
}

// Pass 2: out = sigmoid(out + ws0 + ws1 + ws2), streaming.
__global__ __launch_bounds__(256) void reduce_sigmoid(
    const float* __restrict__ partw, float* __restrict__ out)
{
    const int i = blockIdx.x * 256 + threadIdx.x;     // float4 index
    if (i >= (6 * EDGES) / 4) return;
    const float4* p0 = (const float4*)out;
    const float4* p1 = (const float4*)(partw);
    const float4* p2 = (const float4*)(partw + (size_t)6 * EDGES);
    const float4* p3 = (const float4*)(partw + (size_t)12 * EDGES);
    float4 v = p0[i], a = p1[i], b = p2[i], c = p3[i];
    v.x += a.x + b.x + c.x;  v.y += a.y + b.y + c.y;
    v.z += a.z + b.z + c.z;  v.w += a.w + b.w + c.w;
    v.x = 1.0f / (1.0f + __expf(-v.x));
    v.y = 1.0f / (1.0f + __expf(-v.y));
    v.z = 1.0f / (1.0f + __expf(-v.z));
    v.w = 1.0f / (1.0f + __expf(-v.w));
    ((float4*)out)[i] = v;
}

// ---- fallback (atomic path) if ws is too small ----
__global__ __launch_bounds__(256) void distmult_atomic(
    const float* __restrict__ h_drug, const float* __restrict__ h_disease,
    const float* __restrict__ W,
    const int* __restrict__ drug_src, const int* __restrict__ dis_dst,
    const int* __restrict__ dis_src, const int* __restrict__ drug_dst,
    float* __restrict__ out)
{
    const int b = blockIdx.x;
    const int slot = b & 7, chunk = slot >> 1, half = slot & 1;
    const int j = b >> 3;
    const int ro = j / BATCH, batch = j % BATCH;
    const int eg = threadIdx.x >> 3, lane = threadIdx.x & 7;

    const float* tabA; const float* tabB;
    const int* idxA; const int* idxB;
    if (ro < NREL) {
        tabA = h_drug;    tabB = h_disease;
        idxA = drug_src + (size_t)ro * EDGES;
        idxB = dis_dst  + (size_t)ro * EDGES;
    } else {
        tabA = h_disease; tabB = h_drug;
        idxA = dis_src  + (size_t)(ro - NREL) * EDGES;
        idxB = drug_dst + (size_t)(ro - NREL) * EDGES;
    }
    const int off = chunk * CHUNKF;
    const float4 w4 = ((const float4*)(W + (size_t)ro * DIM + off))[lane];

    #pragma unroll
    for (int p = 0; p < PASSES; ++p) {
        const int e = batch * (PASSES * 64) + p * 64 + half * 32 + eg;
        const int ia = __builtin_nontemporal_load(idxA + e);
        const int ib = __builtin_nontemporal_load(idxB + e);
        const float4 a4 = ((const float4*)(tabA + (size_t)ia * DIM + off))[lane];
        const float4 b4 = ((const float4*)(tabB + (size_t)ib * DIM + off))[lane];
        float s = a4.x * w4.x * b4.x + a4.y * w4.y * b4.y
                + a4.z * w4.z * b4.z + a4.w * w4.w * b4.w;
        s += __shfl_xor(s, 4, 64);
        s += __shfl_xor(s, 2, 64);
        s += __shfl_xor(s, 1, 64);
        if (lane == 0) atomicAdd(&out[(size_t)ro * EDGES + e], s);
    }
}

__global__ __launch_bounds__(256) void sigmoid_inplace(float* __restrict__ out)
{
    const int i = blockIdx.x * 256 + threadIdx.x;
    if (i >= (6 * EDGES) / 4) return;
    float4 v = ((float4*)out)[i];
    v.x = 1.0f / (1.0f + __expf(-v.x));
    v.y = 1.0f / (1.0f + __expf(-v.y));
    v.z = 1.0f / (1.0f + __expf(-v.z));
    v.w = 1.0f / (1.0f + __expf(-v.w));
    ((float4*)out)[i] = v;
}

extern "C" void kernel_launch(void* const* d_in, const int* in_sizes, int n_in,
                              void* d_out, int out_size, void* d_ws, size_t ws_size,
                              hipStream_t stream) {
    const float* h_drug    = (const float*)d_in[0];
    const float* h_disease = (const float*)d_in[1];
    const float* W         = (const float*)d_in[2];
    const int*   drug_src  = (const int*)d_in[3];
    const int*   dis_dst   = (const int*)d_in[4];
    const int*   dis_src   = (const int*)d_in[5];
    const int*   drug_dst  = (const int*)d_in[6];
    float*       out       = (float*)d_out;

    const int n4 = (6 * EDGES) / 4;                    // 300000
    const size_t ws_need = (size_t)3 * 6 * EDGES * sizeof(float);  // 14.4 MB

    if (ws_size >= ws_need) {
        distmult_partial<<<8 * JPER, 256, 0, stream>>>(
            h_drug, h_disease, W, drug_src, dis_dst, dis_src, drug_dst,
            out, (float*)d_ws);
        reduce_sigmoid<<<(n4 + 255) / 256, 256, 0, stream>>>((float*)d_ws, out);
    } else {
        hipMemsetAsync(out, 0, (size_t)6 * EDGES * sizeof(float), stream);
        distmult_atomic<<<8 * JPER, 256, 0, stream>>>(
            h_drug, h_disease, W, drug_src, dis_dst, dis_src, drug_dst, out);
        sigmoid_inplace<<<(n4 + 255) / 256, 256, 0, stream>>>(out);
    }
}

// Round 5
// 124.494 us; speedup vs baseline: 1.6354x; 1.3023x over previous
//
#include <hip/hip_runtime.h>
#include <hip/hip_fp16.h>
#include <math.h>

#define NREL    3
#define EDGES   200000
#define DIM     128
#define PASSES  5
#define UNITS   6250          // EDGES / 32
#define BJ      313           // ceil(UNITS / (4*PASSES))
#define JPER    (6 * BJ)      // (ro, bj) pairs per XCD slot

#define NDRUG   8000
#define NDIS    18000
#define DRUG_ELEMS (NDRUG * DIM)             // 1,024,000
#define TOT_ELEMS  ((NDRUG + NDIS) * DIM)    // 3,328,000

typedef _Float16 half8 __attribute__((ext_vector_type(8)));

// Pre-pass: fp32 tables -> fp16 (concatenated [drug | disease]) in d_ws.
__global__ __launch_bounds__(256) void convert_fp16(
    const float* __restrict__ drug, const float* __restrict__ dis,
    _Float16* __restrict__ o)
{
    const int i = blockIdx.x * 256 + threadIdx.x;   // half8 index
    const int nd8 = DRUG_ELEMS / 8, nt8 = TOT_ELEMS / 8;
    if (i >= nt8) return;
    const float4* s; int j;
    if (i < nd8) { s = (const float4*)drug; j = i * 2; }
    else         { s = (const float4*)dis;  j = (i - nd8) * 2; }
    const float4 x = s[j], y = s[j + 1];
    half8 h;
    h[0] = (_Float16)x.x; h[1] = (_Float16)x.y;
    h[2] = (_Float16)x.z; h[3] = (_Float16)x.w;
    h[4] = (_Float16)y.x; h[5] = (_Float16)y.y;
    h[6] = (_Float16)y.z; h[7] = (_Float16)y.w;
    ((half8*)o)[i] = h;
}

// Gather: 2 chunks of 64 dims (128 B fp16). chunk pinned to an XCD quad via
// blockIdx%8 (XCD pinning verified R2: FETCH 418->32 MB). Halves both bytes
// and 64-B line-requests vs the fp32 version (the R4-identified limiter).
// W stays fp32; accumulation fp32.
__global__ __launch_bounds__(256) void distmult_fp16(
    const _Float16* __restrict__ tabs,   // [drug fp16 | disease fp16]
    const float* __restrict__ W,
    const int* __restrict__ drug_src, const int* __restrict__ dis_dst,
    const int* __restrict__ dis_src,  const int* __restrict__ drug_dst,
    float* __restrict__ part0,           // = d_out, chunk-0 partials
    float* __restrict__ part1)           // = ws,    chunk-1 partials
{
    const int b     = blockIdx.x;
    const int slot  = b & 7;        // XCD slot
    const int chunk = slot >> 2;    // 0..1 -> dims [64*chunk, +64)
    const int q     = slot & 3;     // 4 XCDs per chunk share the edge units
    const int j     = b >> 3;
    const int ro    = j / BJ;       // 0..5 (0..2 fwd, 3..5 rev)
    const int bj    = j % BJ;

    const int eg   = threadIdx.x >> 3;  // 0..31 edge within pass
    const int lane = threadIdx.x & 7;   // 0..7: 8 halfs (16 B) per lane

    const _Float16* tabD = tabs;
    const _Float16* tabS = tabs + DRUG_ELEMS;
    const _Float16 *tabA, *tabB; const int *idxA, *idxB;
    if (ro < NREL) {
        tabA = tabD; tabB = tabS;
        idxA = drug_src + ro * EDGES;
        idxB = dis_dst  + ro * EDGES;
    } else {
        tabA = tabS; tabB = tabD;
        idxA = dis_src  + (ro - NREL) * EDGES;
        idxB = drug_dst + (ro - NREL) * EDGES;
    }

    const int off = chunk * 64 + lane * 8;            // element offset in row
    const float4 wlo = *(const float4*)(W + ro * DIM + off);
    const float4 whi = *(const float4*)(W + ro * DIM + off + 4);
    float* pbase = (chunk == 0 ? part0 : part1) + (size_t)ro * EDGES;

    // Stage 1: all index loads in flight (units may clamp at the tail).
    int e[PASSES], valid[PASSES], ia[PASSES], ib[PASSES];
    #pragma unroll
    for (int p = 0; p < PASSES; ++p) {
        int u = q + 4 * (p + PASSES * bj);
        valid[p] = (u < UNITS);
        const int uc = valid[p] ? u : (UNITS - 1);
        e[p]  = uc * 32 + eg;
        ia[p] = __builtin_nontemporal_load(idxA + e[p]);
        ib[p] = __builtin_nontemporal_load(idxB + e[p]);
    }

    // Stage 2: all row loads in flight (10 x 16 B per thread).
    half8 a8[PASSES], b8[PASSES];
    #pragma unroll
    for (int p = 0; p < PASSES; ++p) {
        a8[p] = *(const half8*)(tabA + ia[p] * DIM + off);
        b8[p] = *(const half8*)(tabB + ib[p] * DIM + off);
    }

    // Stage 3: triple-dot, 8-lane reduce, store.
    #pragma unroll
    for (int p = 0; p < PASSES; ++p) {
        float s = (float)a8[p][0] * wlo.x * (float)b8[p][0]
                + (float)a8[p][1] * wlo.y * (float)b8[p][1]
                + (float)a8[p][2] * wlo.z * (float)b8[p][2]
                + (float)a8[p][3] * wlo.w * (float)b8[p][3]
                + (float)a8[p][4] * whi.x * (float)b8[p][4]
                + (float)a8[p][5] * whi.y * (float)b8[p][5]
                + (float)a8[p][6] * whi.z * (float)b8[p][6]
                + (float)a8[p][7] * whi.w * (float)b8[p][7];
        s += __shfl_xor(s, 4, 64);
        s += __shfl_xor(s, 2, 64);
        s += __shfl_xor(s, 1, 64);
        if (lane == 0 && valid[p])
            __builtin_nontemporal_store(s, pbase + e[p]);
    }
}

// Pass 3: out = sigmoid(out + part1), streaming.
__global__ __launch_bounds__(256) void reduce_sigmoid(
    const float* __restrict__ part1, float* __restrict__ out)
{
    const int i = blockIdx.x * 256 + threadIdx.x;     // float4 index
    if (i >= (6 * EDGES) / 4) return;
    float4 v = ((const float4*)out)[i];
    const float4 a = ((const float4*)part1)[i];
    v.x = 1.0f / (1.0f + __expf(-(v.x + a.x)));
    v.y = 1.0f / (1.0f + __expf(-(v.y + a.y)));
    v.z = 1.0f / (1.0f + __expf(-(v.z + a.z)));
    v.w = 1.0f / (1.0f + __expf(-(v.w + a.w)));
    ((float4*)out)[i] = v;
}

// ---- fallback (fp32 atomic path) if ws is too small ----
__global__ __launch_bounds__(256) void distmult_atomic(
    const float* __restrict__ h_drug, const float* __restrict__ h_disease,
    const float* __restrict__ W,
    const int* __restrict__ drug_src, const int* __restrict__ dis_dst,
    const int* __restrict__ dis_src, const int* __restrict__ drug_dst,
    float* __restrict__ out)
{
    const int b = blockIdx.x;
    const int slot = b & 7, chunk = slot >> 1, half = slot & 1;
    const int j = b >> 3;
    const int ro = j / 625, batch = j % 625;
    const int eg = threadIdx.x >> 3, lane = threadIdx.x & 7;

    const float* tabA; const float* tabB;
    const int* idxA; const int* idxB;
    if (ro < NREL) {
        tabA = h_drug;    tabB = h_disease;
        idxA = drug_src + (size_t)ro * EDGES;
        idxB = dis_dst  + (size_t)ro * EDGES;
    } else {
        tabA = h_disease; tabB = h_drug;
        idxA = dis_src  + (size_t)(ro - NREL) * EDGES;
        idxB = drug_dst + (size_t)(ro - NREL) * EDGES;
    }
    const int off = chunk * 32;
    const float4 w4 = ((const float4*)(W + (size_t)ro * DIM + off))[lane];

    #pragma unroll
    for (int p = 0; p < 5; ++p) {
        const int e = batch * 320 + p * 64 + half * 32 + eg;
        const int ia = __builtin_nontemporal_load(idxA + e);
        const int ib = __builtin_nontemporal_load(idxB + e);
        const float4 a4 = ((const float4*)(tabA + (size_t)ia * DIM + off))[lane];
        const float4 b4 = ((const float4*)(tabB + (size_t)ib * DIM + off))[lane];
        float s = a4.x * w4.x * b4.x + a4.y * w4.y * b4.y
                + a4.z * w4.z * b4.z + a4.w * w4.w * b4.w;
        s += __shfl_xor(s, 4, 64);
        s += __shfl_xor(s, 2, 64);
        s += __shfl_xor(s, 1, 64);
        if (lane == 0) atomicAdd(&out[(size_t)ro * EDGES + e], s);
    }
}

__global__ __launch_bounds__(256) void sigmoid_inplace(float* __restrict__ out)
{
    const int i = blockIdx.x * 256 + threadIdx.x;
    if (i >= (6 * EDGES) / 4) return;
    float4 v = ((float4*)out)[i];
    v.x = 1.0f / (1.0f + __expf(-v.x));
    v.y = 1.0f / (1.0f + __expf(-v.y));
    v.z = 1.0f / (1.0f + __expf(-v.z));
    v.w = 1.0f / (1.0f + __expf(-v.w));
    ((float4*)out)[i] = v;
}

extern "C" void kernel_launch(void* const* d_in, const int* in_sizes, int n_in,
                              void* d_out, int out_size, void* d_ws, size_t ws_size,
                              hipStream_t stream) {
    const float* h_drug    = (const float*)d_in[0];
    const float* h_disease = (const float*)d_in[1];
    const float* W         = (const float*)d_in[2];
    const int*   drug_src  = (const int*)d_in[3];
    const int*   dis_dst   = (const int*)d_in[4];
    const int*   dis_src   = (const int*)d_in[5];
    const int*   drug_dst  = (const int*)d_in[6];
    float*       out       = (float*)d_out;

    const int n4 = (6 * EDGES) / 4;                       // 300000
    const size_t tab_bytes = (size_t)TOT_ELEMS * 2;       // 6,656,000
    const size_t ws_need   = tab_bytes + (size_t)6 * EDGES * sizeof(float); // 11.46 MB

    if (ws_size >= ws_need) {
        _Float16* tabs  = (_Float16*)d_ws;
        float*    part1 = (float*)((char*)d_ws + tab_bytes);

        convert_fp16<<<(TOT_ELEMS / 8 + 255) / 256, 256, 0, stream>>>(
            h_drug, h_disease, tabs);
        distmult_fp16<<<8 * JPER, 256, 0, stream>>>(
            tabs, W, drug_src, dis_dst, dis_src, drug_dst, out, part1);
        reduce_sigmoid<<<(n4 + 255) / 256, 256, 0, stream>>>(part1, out);
    } else {
        hipMemsetAsync(out, 0, (size_t)6 * EDGES * sizeof(float), stream);
        distmult_atomic<<<8 * 6 * 625, 256, 0, stream>>>(
            h_drug, h_disease, W, drug_src, dis_dst, dis_src, drug_dst, out);
        sigmoid_inplace<<<(n4 + 255) / 256, 256, 0, stream>>>(out);
    }
}